// Round 7
// baseline (137.673 us; speedup 1.0000x reference)
//
#include <hip/hip_runtime.h>
#include <stdint.h>

#define NB 2
#define NS 2048
#define NHK 8
#define ND 128
#define NWIN 1024

using bf16x8 = __bf16 __attribute__((ext_vector_type(8)));
using f32x4  = float  __attribute__((ext_vector_type(4)));
using f32x2  = float  __attribute__((ext_vector_type(2)));
using f32x8  = float  __attribute__((ext_vector_type(8)));
using f32x16 = float  __attribute__((ext_vector_type(16)));
using u16x8  = unsigned short __attribute__((ext_vector_type(8)));
using u32x4  = unsigned int   __attribute__((ext_vector_type(4)));

#define L2_10K (13.287712379549449f / 64.0f)  // log2(10000)/64
#define MASKV (-3.0e38f)

static __device__ __forceinline__ float ex2(float x) {
  return __builtin_amdgcn_exp2f(x);
}

static __device__ __forceinline__ unsigned short f2bf(float x) {
  unsigned int u = __builtin_bit_cast(unsigned int, x);
  u += 0x7FFFu + ((u >> 16) & 1u);
  return (unsigned short)(u >> 16);
}

static __device__ __forceinline__ unsigned int cvtpk(float lo, float hi) {
  unsigned int r;
  asm("v_cvt_pk_bf16_f32 %0, %1, %2" : "=v"(r) : "v"(lo), "v"(hi));
  return r;
}

static __device__ __forceinline__ void gll16(const void* g, void* l) {
  __builtin_amdgcn_global_load_lds(
      (const __attribute__((address_space(1))) void*)g,
      (__attribute__((address_space(3))) void*)l, 16, 0, 0);
}

#define MFMA32(a, b, c) __builtin_amdgcn_mfma_f32_32x32x16_bf16((a), (b), (c), 0, 0, 0)

// ---------------- cos/sin table: tab[p][0..63]=cos, [64..127]=sin ----------------
__global__ __launch_bounds__(64) void build_tab(float* __restrict__ tab) {
  const int p = blockIdx.x, f = threadIdx.x;
  float s, c;
  __sincosf((float)p * ex2(-(float)f * L2_10K), &s, &c);
  tab[(size_t)p * 128 + f] = c;
  tab[(size_t)p * 128 + 64 + f] = s;
}

// ---------------- prepass: per-tile K (roped, swizzled) and V ([d][key] swz) images ----
// K image 8192B: row j (256B) holds 16B chunk c at slot (c ^ (j&7)); chunk c = d 8c..8c+7.
// V image 8192B: row d (64B) holds 16B chunk c (keys 8c..8c+7) at slot (c ^ ((d>>1)&3)).
__global__ __launch_bounds__(256) void prepass(
    const float* __restrict__ kin, const float* __restrict__ vin,
    const int* __restrict__ pos, const float* __restrict__ tab,
    unsigned short* __restrict__ kimg, unsigned short* __restrict__ vimg) {
  const int bid = blockIdx.x;
  const int ti = bid & 63, gidx = bid >> 6;
  const int hk = gidx & 7, b = gidx >> 3;
  const int t = threadIdx.x;

  unsigned short* kout = kimg + (size_t)bid * 4096;
#pragma unroll
  for (int uu = 0; uu < 2; ++uu) {
    const int u = t * 2 + uu;
    const int j = u >> 4;
    const int d0 = ((u & 15) << 3) ^ ((j & 7) << 3);  // u16 index
    const int tok = (b << 11) + (ti << 5) + j;
    const float* kp = kin + (size_t)tok * (NHK * ND) + hk * ND;
    f32x8 a = *(const f32x8*)(kp + d0);
    f32x8 p = *(const f32x8*)(kp + (d0 ^ 64));
    const float* tr = tab + (size_t)(pos[tok] & 2047) * 128 + (d0 & 63);
    f32x8 c8 = *(const f32x8*)tr;
    f32x8 s8 = *(const f32x8*)(tr + 64);
    u16x8 o;
#pragma unroll
    for (int i = 0; i < 8; ++i) {
      float val = (d0 < 64) ? (a[i] * c8[i] - p[i] * s8[i])
                            : (a[i] * c8[i] + p[i] * s8[i]);
      o[i] = f2bf(val);
    }
    *(u16x8*)(kout + (size_t)u * 8) = o;
  }

  unsigned short* vout = vimg + (size_t)bid * 4096;
  {
    const int d0 = (t >> 2) << 1;
    const int kp4 = t & 3;
    const int tok0 = (b << 11) + (ti << 5) + (kp4 << 3);
    const float* vp = vin + (size_t)tok0 * (NHK * ND) + hk * ND + d0;
    u16x8 lo, hi;
#pragma unroll
    for (int i = 0; i < 8; ++i) {
      f32x2 r = *(const f32x2*)(vp + (size_t)i * (NHK * ND));
      lo[i] = f2bf(r[0]);
      hi[i] = f2bf(r[1]);
    }
    const int sub = kp4 ^ ((d0 >> 1) & 3);
    *(u16x8*)(vout + d0 * 32 + sub * 8) = lo;
    *(u16x8*)(vout + (d0 + 1) * 32 + sub * 8) = hi;
  }
}

// ---------------- fused flash attention (32x32 MFMA, 4 waves, 2-slot) ----------
// 256 thr = 4 waves (one per g). Wave: 32 q-rows x D=128 via mfma_32x32x16.
// S^T = mfma(K, Q): lane(q=lane&31, hi): reg r -> key (r&3)+8*(r>>2)+4*hi.
// O^T = mfma(V^T, P^T): reg r of dtile -> d = dt*32+(r&3)+8*(r>>2)+4*hi, col q.
template <bool PRE>
__global__ __launch_bounds__(256, 4) void attn_fwd(
    const float* __restrict__ qin, const float* __restrict__ kin,
    const float* __restrict__ vin, const int* __restrict__ pos,
    const char* __restrict__ kimg, const char* __restrict__ vimg,
    const float* __restrict__ tab, float* __restrict__ out) {
  __shared__ __align__(16) char Kb[2][8192];
  __shared__ __align__(16) char Vb[2][8192];

  const int B = blockIdx.x;
  // XCD swizzle: 64 q-tiles of one (b,hk) group on one XCD; heavy/light interleave
  const int group = (B & 7) + ((B >> 9) << 3);
  const int qi = (B >> 3) & 63;
  const int qt = (qi & 1) ? (qi >> 1) : (63 - (qi >> 1));
  const int hk = group & 7, b = group >> 3;

  const int tid = threadIdx.x;
  const int w = tid >> 6, lane = tid & 63;
  const int r32 = lane & 31, hi = lane >> 5;
  const int g = w;
  const int q0b = qt << 5;
  int lo = q0b - (NWIN - 1);
  if (lo < 0) lo = 0;
  lo &= ~31;
  const int ti0 = lo >> 5;
  const int nt = (q0b >> 5) - ti0 + 1;

  // single 32-bit global offset (uniform 64-bit bases stay in SGPRs)
  const int gvoff = group * 64 * 8192 + (w * 128 + lane) * 16;

  auto stage = [&](int sl, int ti) {
    if constexpr (PRE) {
      const int off = gvoff + ti * 8192;
      char* kd = &Kb[sl][w * 2048];
      char* vd = &Vb[sl][w * 2048];
      gll16(kimg + off, kd);
      gll16(kimg + off + 1024, kd + 1024);
      gll16(vimg + off, vd);
      gll16(vimg + off + 1024, vd + 1024);
    } else {
      // K: rope inline, image-format swizzled writes
      const int j = tid >> 3;
      const int du = (tid & 7) << 4;
      const int tok = (b << 11) + (ti << 5) + j;
      const float* kp = kin + (size_t)tok * (NHK * ND) + hk * ND;
      const float pj = (float)pos[tok];
#pragma unroll
      for (int gq = 0; gq < 2; ++gq) {
        const int dd = du + gq * 8;
        f32x8 a = *(const f32x8*)(kp + dd);
        f32x8 p = *(const f32x8*)(kp + (dd ^ 64));
        u16x8 o;
#pragma unroll
        for (int i = 0; i < 8; ++i) {
          float s, c;
          __sincosf(pj * ex2(-(float)((dd & 63) + i) * L2_10K), &s, &c);
          float val = (dd < 64) ? (a[i] * c - p[i] * s) : (a[i] * c + p[i] * s);
          o[i] = f2bf(val);
        }
        *(u16x8*)(&Kb[sl][((j << 8) + (dd << 1)) ^ ((j & 7) << 4)]) = o;
      }
      // V: [d][key] with chunk swizzle
      const int d0 = (tid >> 2) << 1;
      const int kp4 = tid & 3;
      const float* vp = vin + (size_t)((b << 11) + (ti << 5) + (kp4 << 3)) * (NHK * ND) + hk * ND + d0;
      u16x8 lov, hiv;
#pragma unroll
      for (int i = 0; i < 8; ++i) {
        f32x2 r = *(const f32x2*)(vp + (size_t)i * (NHK * ND));
        lov[i] = f2bf(r[0]);
        hiv[i] = f2bf(r[1]);
      }
      const int sub = kp4 ^ ((d0 >> 1) & 3);
      unsigned short* vb16 = (unsigned short*)Vb[sl];
      *(u16x8*)(vb16 + d0 * 32 + sub * 8) = lov;
      *(u16x8*)(vb16 + (d0 + 1) * 32 + sub * 8) = hiv;
    }
  };

  // prologue: stage tile 0 into slot 0 (overlaps Q rope)
  stage(0, ti0);

  // ---- Q fragments (B-operand): lane(q=r32, hi), frag m covers d = 16m+8hi..+7 ----
  const float QSC = 0.08838834764831845f * 1.4426950408889634f;
  bf16x8 qfr[8];
  {
    const int qrow = q0b + r32;
    const size_t tokq = (size_t)(b << 11) + qrow;
    const float* qp = qin + tokq * 4096 + (hk * 4 + g) * 128;
    const int posq = pos[tokq] & 2047;
#pragma unroll
    for (int m = 0; m < 4; ++m) {
      const int dlo = (m << 4) + (hi << 3);  // < 64
      f32x8 lo8 = *(const f32x8*)(qp + dlo);
      f32x8 hi8 = *(const f32x8*)(qp + dlo + 64);
      f32x8 cc, ss;
      if constexpr (PRE) {
        const float* tp = tab + (size_t)posq * 128 + dlo;
        cc = *(const f32x8*)tp;
        ss = *(const f32x8*)(tp + 64);
      } else {
        const float pf = (float)posq;
#pragma unroll
        for (int i = 0; i < 8; ++i) {
          float s, c;
          __sincosf(pf * ex2(-(float)(dlo + i) * L2_10K), &s, &c);
          cc[i] = c;
          ss[i] = s;
        }
      }
      u16x8 ulo, uhi;
#pragma unroll
      for (int i = 0; i < 8; ++i) {
        ulo[i] = f2bf((lo8[i] * cc[i] - hi8[i] * ss[i]) * QSC);
        uhi[i] = f2bf((hi8[i] * cc[i] + lo8[i] * ss[i]) * QSC);
      }
      qfr[m] = __builtin_bit_cast(bf16x8, ulo);
      qfr[m + 4] = __builtin_bit_cast(bf16x8, uhi);
    }
  }

  f32x16 Oc[4] = {};
  float msh = -1e30f;   // running max for this lane's q-row
  float lsum = 0.0f;    // this lane's partial (its 16 keys/tile half)

  // K read: addr_m = kx ^ (m<<5); kx = r32*256 | (hi^(sw&1))<<4 | (sw>>1)<<5, sw=r32&7
  const int kx = (r32 << 8) | ((hi ^ (r32 & 1)) << 4) | (((r32 & 7) >> 1) << 5);
  // V read: row d=dt*32+r32, chunk slot = (2ks+hi) ^ ((r32>>1)&3)  (dt-independent)
  const int vsz = (r32 >> 1) & 3;
  const int vbase0 = r32 * 64;

  for (int t = 0; t < nt; ++t) {
    __syncthreads();  // drains vmcnt: stage(t) resident; all waves done reading slot (t+1)&1
    if (t + 1 < nt) stage((t + 1) & 1, ti0 + t + 1);

    const int j0 = (ti0 + t) << 5;
    const char* KB = Kb[t & 1];
    const char* VB = Vb[t & 1];

    // ---- S^T = K Q^T : one 32x32 accumulator ----
    f32x16 sT = {};
    __builtin_amdgcn_s_setprio(1);
#pragma unroll
    for (int m = 0; m < 8; ++m) {
      const bf16x8 kf = *(const bf16x8*)(KB + (kx ^ (m << 5)));
      sT = MFMA32(kf, qfr[m], sT);
    }
    __builtin_amdgcn_s_setprio(0);

    // ---- mask only boundary tiles (wave-uniform branch) ----
    if ((j0 >= q0b) || (j0 < q0b - 992)) {
      const int irow = q0b + r32;
#pragma unroll
      for (int r = 0; r < 16; ++r) {
        const int j = j0 + (r & 3) + 8 * (r >> 2) + 4 * hi;
        if (!(j <= irow && irow - j < NWIN)) sT[r] = MASKV;
      }
    }

    // ---- online softmax: deferred-max fast path (pure per-lane) ----
    float pm = sT[0];
#pragma unroll
    for (int r = 1; r < 16; ++r) pm = fmaxf(pm, sT[r]);
    if (__any(pm - msh > 8.0f)) {  // slow path: true row max + rescale
      float M = fmaxf(pm, __shfl_xor(pm, 32));
      const float mn = fmaxf(msh, M);
      const float co = ex2(msh - mn);  // same on both hi-partners
      msh = mn;
      lsum *= co;
#pragma unroll
      for (int dt = 0; dt < 4; ++dt)
#pragma unroll
        for (int r = 0; r < 16; ++r) Oc[dt][r] *= co;
    }
#pragma unroll
    for (int r = 0; r < 16; ++r) sT[r] = ex2(sT[r] - msh);
    lsum += (((sT[0] + sT[1]) + (sT[2] + sT[3])) + ((sT[4] + sT[5]) + (sT[6] + sT[7]))) +
            (((sT[8] + sT[9]) + (sT[10] + sT[11])) + ((sT[12] + sT[13]) + (sT[14] + sT[15])));

    // quads: A[s][j] covers keys 8s+4hi+{2j,2j+1}
    unsigned int A00 = cvtpk(sT[0], sT[1]),   A01 = cvtpk(sT[2], sT[3]);
    unsigned int A10 = cvtpk(sT[4], sT[5]),   A11 = cvtpk(sT[6], sT[7]);
    unsigned int A20 = cvtpk(sT[8], sT[9]),   A21 = cvtpk(sT[10], sT[11]);
    unsigned int A30 = cvtpk(sT[12], sT[13]), A31 = cvtpk(sT[14], sT[15]);

    // ---- P V : O^T[d][q], kstep 0 then 1 ----
    __builtin_amdgcn_s_setprio(1);
#pragma unroll
    for (int ks = 0; ks < 2; ++ks) {
      unsigned int w0 = ks ? A20 : A00, w1 = ks ? A21 : A01;
      unsigned int w2 = ks ? A30 : A10, w3 = ks ? A31 : A11;
      asm volatile("v_permlane32_swap_b32 %0, %1" : "+v"(w0), "+v"(w2));
      asm volatile("v_permlane32_swap_b32 %0, %1" : "+v"(w1), "+v"(w3));
      u32x4 pk4 = {w0, w1, w2, w3};
      const bf16x8 pb = __builtin_bit_cast(bf16x8, pk4);
      const int vslot = (((ks << 1) | hi) ^ vsz) << 4;
#pragma unroll
      for (int dt = 0; dt < 4; ++dt) {
        const bf16x8 vf = *(const bf16x8*)(VB + (dt << 11) + vbase0 + vslot);
        Oc[dt] = MFMA32(vf, pb, Oc[dt]);
      }
    }
    __builtin_amdgcn_s_setprio(0);
  }

  // ---- epilogue: row-sum across hi-partners, normalize, vectorized stores ----
  float ls = lsum + __shfl_xor(lsum, 32);
  const float rl = 1.0f / ls;
  float* op = out + ((size_t)(b << 11) + q0b + r32) * 4096 + (hk * 4 + g) * 128 + (hi << 2);
#pragma unroll
  for (int dt = 0; dt < 4; ++dt)
#pragma unroll
    for (int s = 0; s < 4; ++s) {
      f32x4 o = {Oc[dt][4 * s + 0] * rl, Oc[dt][4 * s + 1] * rl,
                 Oc[dt][4 * s + 2] * rl, Oc[dt][4 * s + 3] * rl};
      *(f32x4*)(op + (dt << 5) + (s << 3)) = o;
    }
}

extern "C" void kernel_launch(void* const* d_in, const int* in_sizes, int n_in,
                              void* d_out, int out_size, void* d_ws, size_t ws_size,
                              hipStream_t stream) {
  const float* q = (const float*)d_in[0];
  const float* k = (const float*)d_in[1];
  const float* v = (const float*)d_in[2];
  const int* pos = (const int*)d_in[3];
  float* out = (float*)d_out;

  const size_t TAB = (size_t)2048 * 128 * 4;        // 1MB cos/sin table
  const size_t KIMG = (size_t)16 * 64 * 8192;       // 8MB per image
  const size_t need = TAB + 2 * KIMG;

  if (ws_size >= need) {
    float* tab = (float*)d_ws;
    char* kimg = (char*)d_ws + TAB;
    char* vimg = kimg + KIMG;
    build_tab<<<2048, 64, 0, stream>>>(tab);
    prepass<<<1024, 256, 0, stream>>>(k, v, pos, tab,
                                      (unsigned short*)kimg, (unsigned short*)vimg);
    attn_fwd<true><<<1024, 256, 0, stream>>>(q, k, v, pos, kimg, vimg, tab, out);
  } else {
    attn_fwd<false><<<1024, 256, 0, stream>>>(q, k, v, pos, nullptr, nullptr, nullptr, out);
  }
}

// Round 8
// 130.754 us; speedup vs baseline: 1.0529x; 1.0529x over previous
//
#include <hip/hip_runtime.h>
#include <stdint.h>

#define NB 2
#define NS 2048
#define NHK 8
#define ND 128
#define NWIN 1024

using bf16x8 = __bf16 __attribute__((ext_vector_type(8)));
using f32x4  = float  __attribute__((ext_vector_type(4)));
using f32x2  = float  __attribute__((ext_vector_type(2)));
using f32x8  = float  __attribute__((ext_vector_type(8)));
using f32x16 = float  __attribute__((ext_vector_type(16)));
using u16x8  = unsigned short __attribute__((ext_vector_type(8)));
using u32x4  = unsigned int   __attribute__((ext_vector_type(4)));

#define L2_10K (13.287712379549449f / 64.0f)  // log2(10000)/64
#define MASKV (-3.0e38f)

static __device__ __forceinline__ float ex2(float x) {
  return __builtin_amdgcn_exp2f(x);
}

static __device__ __forceinline__ unsigned short f2bf(float x) {
  unsigned int u = __builtin_bit_cast(unsigned int, x);
  u += 0x7FFFu + ((u >> 16) & 1u);
  return (unsigned short)(u >> 16);
}

static __device__ __forceinline__ unsigned int cvtpk(float lo, float hi) {
  unsigned int r;
  asm("v_cvt_pk_bf16_f32 %0, %1, %2" : "=v"(r) : "v"(lo), "v"(hi));
  return r;
}

#define MFMA32(a, b, c) __builtin_amdgcn_mfma_f32_32x32x16_bf16((a), (b), (c), 0, 0, 0)

// ---------------- cos/sin table: tab[p][0..63]=cos, [64..127]=sin ----------------
__global__ __launch_bounds__(64) void build_tab(float* __restrict__ tab) {
  const int p = blockIdx.x, f = threadIdx.x;
  float s, c;
  __sincosf((float)p * ex2(-(float)f * L2_10K), &s, &c);
  tab[(size_t)p * 128 + f] = c;
  tab[(size_t)p * 128 + 64 + f] = s;
}

// ---------------- prepass: wave-coalesced fragment images ----------------
// Per (group=b*8+hk, tile) 8192B each.
// K: chunk (m,hi,key): 16B = roped K[key][d=16m+8hi .. +7], off = m*1024+hi*512+key*16.
// V: chunk (ks,hi,dt,r): 16B = V[key=16ks+8hi+i][d=32dt+r],  off = ks*4096+hi*2048+dt*512+r*16.
__global__ __launch_bounds__(256) void prepass(
    const float* __restrict__ kin, const float* __restrict__ vin,
    const int* __restrict__ pos, const float* __restrict__ tab,
    unsigned short* __restrict__ kimg, unsigned short* __restrict__ vimg) {
  const int bid = blockIdx.x;
  const int ti = bid & 63, gidx = bid >> 6;
  const int hk = gidx & 7, b = gidx >> 3;
  const int t = threadIdx.x;

  // K: thread t covers chunks (m, hi, key) and (m+4, hi, key), m<4
  unsigned short* kout = kimg + (size_t)bid * 4096;
  {
    const int m = t >> 6, hi = (t >> 5) & 1, key = t & 31;
    const int d0 = (m << 4) + (hi << 3);  // < 64
    const int tok = (b << 11) + (ti << 5) + key;
    const float* kp = kin + (size_t)tok * (NHK * ND) + hk * ND;
    f32x8 x1 = *(const f32x8*)(kp + d0);
    f32x8 x2 = *(const f32x8*)(kp + d0 + 64);
    const float* tr = tab + (size_t)(pos[tok] & 2047) * 128 + d0;
    f32x8 c8 = *(const f32x8*)tr;
    f32x8 s8 = *(const f32x8*)(tr + 64);
    u16x8 olo, ohi;
#pragma unroll
    for (int i = 0; i < 8; ++i) {
      olo[i] = f2bf(x1[i] * c8[i] - x2[i] * s8[i]);
      ohi[i] = f2bf(x2[i] * c8[i] + x1[i] * s8[i]);
    }
    *(u16x8*)(kout + (size_t)t * 8) = olo;
    *(u16x8*)(kout + (size_t)(t + 256) * 8) = ohi;
  }

  // V: thread t covers chunks (ks=0, hi, dt, r) and (ks=1, hi, dt, r)
  unsigned short* vout = vimg + (size_t)bid * 4096;
  {
    const int hi = (t >> 7) & 1, dt = (t >> 5) & 3, r = t & 31;
    const int d = (dt << 5) + r;
    const float* vp =
        vin + (size_t)((b << 11) + (ti << 5) + (hi << 3)) * (NHK * ND) + hk * ND + d;
    u16x8 o0, o1;
#pragma unroll
    for (int i = 0; i < 8; ++i) {
      o0[i] = f2bf(vp[(size_t)i * (NHK * ND)]);
      o1[i] = f2bf(vp[(size_t)(16 + i) * (NHK * ND)]);
    }
    *(u16x8*)(vout + (size_t)t * 8) = o0;
    *(u16x8*)(vout + (size_t)(t + 256) * 8) = o1;
  }
}

// ---------------- fused flash attention: 1-wave blocks, direct-from-L2 ----------
// 4096 blocks x 64 thr. Wave = (b,hk,g,qt): 32 q-rows x D=128, mfma_32x32x16.
// No LDS, no barriers: operand fragments read straight from the images
// (fully coalesced 1KB/instr, L2-resident via XCD-grouped scheduling).
template <bool PRE>
__global__ __launch_bounds__(64, 3) void attn_fwd(
    const float* __restrict__ qin, const float* __restrict__ kin,
    const float* __restrict__ vin, const int* __restrict__ pos,
    const char* __restrict__ kimg, const char* __restrict__ vimg,
    const float* __restrict__ tab, float* __restrict__ out) {
  const int B = blockIdx.x;
  const int xcd = B & 7;
  const int idx = B >> 3;                       // 0..511
  const int group = xcd + ((idx >> 8) << 3);    // 2 groups per XCD slot
  const int rem = idx & 255;
  const int qi = rem >> 2, g = rem & 3;
  const int qt = (qi & 1) ? (qi >> 1) : (63 - (qi >> 1));  // heavy/light interleave
  const int hk = group & 7, b = group >> 3;

  const int lane = threadIdx.x & 63;
  const int r32 = lane & 31, hi = lane >> 5;
  const int q0b = qt << 5;
  int lo = q0b - (NWIN - 1);
  if (lo < 0) lo = 0;
  lo &= ~31;
  const int ti0 = lo >> 5;
  const int nt = (q0b >> 5) - ti0 + 1;

  const char* kgb = kimg + (size_t)group * 64 * 8192;
  const char* vgb = vimg + (size_t)group * 64 * 8192;

  // ---- Q fragments (B-operand): lane(q=r32, hi), frag m covers d = 16m+8hi..+7 ----
  const float QSC = 0.08838834764831845f * 1.4426950408889634f;
  bf16x8 qfr[8];
  {
    const int qrow = q0b + r32;
    const size_t tokq = (size_t)(b << 11) + qrow;
    const float* qp = qin + tokq * 4096 + (hk * 4 + g) * 128;
    const int posq = pos[tokq] & 2047;
#pragma unroll
    for (int m = 0; m < 4; ++m) {
      const int dlo = (m << 4) + (hi << 3);  // < 64
      f32x8 lo8 = *(const f32x8*)(qp + dlo);
      f32x8 hi8 = *(const f32x8*)(qp + dlo + 64);
      f32x8 cc, ss;
      if constexpr (PRE) {
        const float* tp = tab + (size_t)posq * 128 + dlo;
        cc = *(const f32x8*)tp;
        ss = *(const f32x8*)(tp + 64);
      } else {
        const float pf = (float)posq;
#pragma unroll
        for (int i = 0; i < 8; ++i) {
          float s, c;
          __sincosf(pf * ex2(-(float)(dlo + i) * L2_10K), &s, &c);
          cc[i] = c;
          ss[i] = s;
        }
      }
      u16x8 ulo, uhi;
#pragma unroll
      for (int i = 0; i < 8; ++i) {
        ulo[i] = f2bf((lo8[i] * cc[i] - hi8[i] * ss[i]) * QSC);
        uhi[i] = f2bf((hi8[i] * cc[i] + lo8[i] * ss[i]) * QSC);
      }
      qfr[m] = __builtin_bit_cast(bf16x8, ulo);
      qfr[m + 4] = __builtin_bit_cast(bf16x8, uhi);
    }
  }

  f32x16 Oc[4] = {};
  float msh = -1e30f;   // running max for this lane's q-row
  float lsum = 0.0f;    // this lane's partial (its 16 keys/tile)

  const int kfo = hi * 512 + r32 * 16;             // K frag: + m*1024
  const int vfo = hi * 2048 + r32 * 16;            // V frag: + ks*4096 + dt*512

  for (int t = 0; t < nt; ++t) {
    const int j0 = (ti0 + t) << 5;
    const char* kt = kgb + (size_t)(ti0 + t) * 8192;
    const char* vt = vgb + (size_t)(ti0 + t) * 8192;

    // ---- K fragments (coalesced 1KB loads) + S^T = K Q^T ----
    bf16x8 kf[8];
    if constexpr (PRE) {
#pragma unroll
      for (int m = 0; m < 8; ++m)
        kf[m] = *(const bf16x8*)(kt + m * 1024 + kfo);
    } else {
      const int tokk = (b << 11) + j0 + r32;
      const float* kp = kin + (size_t)tokk * (NHK * ND) + hk * ND;
      const float pf = (float)(pos[tokk] & 2047);
#pragma unroll
      for (int m = 0; m < 8; ++m) {
        const int d0 = (m << 4) + (hi << 3);
        const int f = d0 & 63;
        f32x8 x1 = *(const f32x8*)(kp + f);
        f32x8 x2 = *(const f32x8*)(kp + f + 64);
        u16x8 o;
#pragma unroll
        for (int i = 0; i < 8; ++i) {
          float s, c;
          __sincosf(pf * ex2(-(float)(f + i) * L2_10K), &s, &c);
          o[i] = f2bf((d0 < 64) ? (x1[i] * c - x2[i] * s)
                                : (x2[i] * c + x1[i] * s));
        }
        kf[m] = __builtin_bit_cast(bf16x8, o);
      }
    }

    f32x16 sT = {};
    __builtin_amdgcn_s_setprio(1);
#pragma unroll
    for (int m = 0; m < 8; ++m) sT = MFMA32(kf[m], qfr[m], sT);
    __builtin_amdgcn_s_setprio(0);

    // ---- V fragments issued now, consumed after softmax (latency hidden) ----
    bf16x8 vf[8];
    if constexpr (PRE) {
#pragma unroll
      for (int u = 0; u < 8; ++u)
        vf[u] = *(const bf16x8*)(vt + (u >> 2) * 4096 + (u & 3) * 512 + vfo);
    } else {
#pragma unroll
      for (int u = 0; u < 8; ++u) {
        const int ks = u >> 2, dt = u & 3;
        u16x8 o;
#pragma unroll
        for (int i = 0; i < 8; ++i) {
          const int tok = (b << 11) + j0 + ks * 16 + hi * 8 + i;
          o[i] = f2bf(vin[(size_t)tok * (NHK * ND) + hk * ND + dt * 32 + r32]);
        }
        vf[u] = __builtin_bit_cast(bf16x8, o);
      }
    }

    // ---- mask only boundary tiles (wave-uniform branch) ----
    if ((j0 >= q0b) || (j0 < q0b - 992)) {
      const int irow = q0b + r32;
#pragma unroll
      for (int r = 0; r < 16; ++r) {
        const int j = j0 + (r & 3) + 8 * (r >> 2) + 4 * hi;
        if (!(j <= irow && irow - j < NWIN)) sT[r] = MASKV;
      }
    }

    // ---- online softmax: deferred-max fast path (pure per-lane) ----
    float pm = sT[0];
#pragma unroll
    for (int r = 1; r < 16; ++r) pm = fmaxf(pm, sT[r]);
    if (__any(pm - msh > 8.0f)) {  // slow path: true row max + rescale
      float M = fmaxf(pm, __shfl_xor(pm, 32));
      const float mn = fmaxf(msh, M);
      const float co = ex2(msh - mn);  // same on both hi-partners
      msh = mn;
      lsum *= co;
#pragma unroll
      for (int dt = 0; dt < 4; ++dt)
#pragma unroll
        for (int r = 0; r < 16; ++r) Oc[dt][r] *= co;
    }
#pragma unroll
    for (int r = 0; r < 16; ++r) sT[r] = ex2(sT[r] - msh);
    lsum += (((sT[0] + sT[1]) + (sT[2] + sT[3])) + ((sT[4] + sT[5]) + (sT[6] + sT[7]))) +
            (((sT[8] + sT[9]) + (sT[10] + sT[11])) + ((sT[12] + sT[13]) + (sT[14] + sT[15])));

    // quads: A[s][j] covers keys 8s+4hi+{2j,2j+1}
    unsigned int A00 = cvtpk(sT[0], sT[1]),   A01 = cvtpk(sT[2], sT[3]);
    unsigned int A10 = cvtpk(sT[4], sT[5]),   A11 = cvtpk(sT[6], sT[7]);
    unsigned int A20 = cvtpk(sT[8], sT[9]),   A21 = cvtpk(sT[10], sT[11]);
    unsigned int A30 = cvtpk(sT[12], sT[13]), A31 = cvtpk(sT[14], sT[15]);

    // ---- P V : O^T[d][q], kstep 0 then 1 ----
    __builtin_amdgcn_s_setprio(1);
#pragma unroll
    for (int ks = 0; ks < 2; ++ks) {
      unsigned int w0 = ks ? A20 : A00, w1 = ks ? A21 : A01;
      unsigned int w2 = ks ? A30 : A10, w3 = ks ? A31 : A11;
      asm volatile("v_permlane32_swap_b32 %0, %1" : "+v"(w0), "+v"(w2));
      asm volatile("v_permlane32_swap_b32 %0, %1" : "+v"(w1), "+v"(w3));
      u32x4 pk4 = {w0, w1, w2, w3};
      const bf16x8 pb = __builtin_bit_cast(bf16x8, pk4);
#pragma unroll
      for (int dt = 0; dt < 4; ++dt)
        Oc[dt] = MFMA32(vf[ks * 4 + dt], pb, Oc[dt]);
    }
    __builtin_amdgcn_s_setprio(0);
  }

  // ---- epilogue: row-sum across hi-partners, normalize, vectorized stores ----
  float ls = lsum + __shfl_xor(lsum, 32);
  const float rl = 1.0f / ls;
  float* op = out + ((size_t)(b << 11) + q0b + r32) * 4096 + (hk * 4 + g) * 128 + (hi << 2);
#pragma unroll
  for (int dt = 0; dt < 4; ++dt)
#pragma unroll
    for (int s = 0; s < 4; ++s) {
      f32x4 o = {Oc[dt][4 * s + 0] * rl, Oc[dt][4 * s + 1] * rl,
                 Oc[dt][4 * s + 2] * rl, Oc[dt][4 * s + 3] * rl};
      *(f32x4*)(op + (dt << 5) + (s << 3)) = o;
    }
}

extern "C" void kernel_launch(void* const* d_in, const int* in_sizes, int n_in,
                              void* d_out, int out_size, void* d_ws, size_t ws_size,
                              hipStream_t stream) {
  const float* q = (const float*)d_in[0];
  const float* k = (const float*)d_in[1];
  const float* v = (const float*)d_in[2];
  const int* pos = (const int*)d_in[3];
  float* out = (float*)d_out;

  const size_t TAB = (size_t)2048 * 128 * 4;        // 1MB cos/sin table
  const size_t KIMG = (size_t)16 * 64 * 8192;       // 8MB per image
  const size_t need = TAB + 2 * KIMG;

  if (ws_size >= need) {
    float* tab = (float*)d_ws;
    char* kimg = (char*)d_ws + TAB;
    char* vimg = kimg + KIMG;
    build_tab<<<2048, 64, 0, stream>>>(tab);
    prepass<<<1024, 256, 0, stream>>>(k, v, pos, tab,
                                      (unsigned short*)kimg, (unsigned short*)vimg);
    attn_fwd<true><<<4096, 64, 0, stream>>>(q, k, v, pos, kimg, vimg, tab, out);
  } else {
    attn_fwd<false><<<4096, 64, 0, stream>>>(q, k, v, pos, nullptr, nullptr, nullptr, out);
  }
}

// Round 9
// 103.337 us; speedup vs baseline: 1.3323x; 1.2653x over previous
//
#include <hip/hip_runtime.h>
#include <stdint.h>

#define NB 2
#define NS 2048
#define NHK 8
#define ND 128
#define NWIN 1024

using bf16x8 = __bf16 __attribute__((ext_vector_type(8)));
using f32x4  = float  __attribute__((ext_vector_type(4)));
using f32x2  = float  __attribute__((ext_vector_type(2)));
using f32x8  = float  __attribute__((ext_vector_type(8)));
using u16x8  = unsigned short __attribute__((ext_vector_type(8)));
using u32x4  = unsigned int   __attribute__((ext_vector_type(4)));

#define L2_10K (13.287712379549449f / 64.0f)  // log2(10000)/64
#define MASKV (-3.0e38f)

static __device__ __forceinline__ float ex2(float x) {
  return __builtin_amdgcn_exp2f(x);
}

static __device__ __forceinline__ unsigned short f2bf(float x) {
  unsigned int u = __builtin_bit_cast(unsigned int, x);
  u += 0x7FFFu + ((u >> 16) & 1u);
  return (unsigned short)(u >> 16);
}

static __device__ __forceinline__ unsigned int cvtpk(float lo, float hi) {
  unsigned int r;
  asm("v_cvt_pk_bf16_f32 %0, %1, %2" : "=v"(r) : "v"(lo), "v"(hi));
  return r;
}

static __device__ __forceinline__ void gll16(const void* g, void* l) {
  __builtin_amdgcn_global_load_lds(
      (const __attribute__((address_space(1))) void*)g,
      (__attribute__((address_space(3))) void*)l, 16, 0, 0);
}

#define MFMA16(a, b, c) __builtin_amdgcn_mfma_f32_16x16x32_bf16((a), (b), (c), 0, 0, 0)

// ---------------- cos/sin table: tab[p][0..63]=cos, [64..127]=sin ----------------
__global__ __launch_bounds__(64) void build_tab(float* __restrict__ tab) {
  const int p = blockIdx.x, f = threadIdx.x;
  float s, c;
  __sincosf((float)p * ex2(-(float)f * L2_10K), &s, &c);
  tab[(size_t)p * 128 + f] = c;
  tab[(size_t)p * 128 + 64 + f] = s;
}

// ---------------- prepass: per-tile K (roped, swizzled) and V ([d][key] swz) images ----
// K image 8192B: row j (256B) holds 16B chunk at ((c)^(j&7)); V image 8192B:
// row d (64B): logical chunk c (keys 8c..8c+7 bf16) at physical slot c^((d>>1)&3).
__global__ __launch_bounds__(256) void prepass(
    const float* __restrict__ kin, const float* __restrict__ vin,
    const int* __restrict__ pos, const float* __restrict__ tab,
    unsigned short* __restrict__ kimg, unsigned short* __restrict__ vimg) {
  const int bid = blockIdx.x;
  const int ti = bid & 63, gidx = bid >> 6;
  const int hk = gidx & 7, b = gidx >> 3;
  const int t = threadIdx.x;

  unsigned short* kout = kimg + (size_t)bid * 4096;
#pragma unroll
  for (int uu = 0; uu < 2; ++uu) {
    const int u = t * 2 + uu;
    const int j = u >> 4;
    const int d0 = ((u & 15) << 3) ^ ((j & 7) << 3);  // u16 index
    const int tok = (b << 11) + (ti << 5) + j;
    const float* kp = kin + (size_t)tok * (NHK * ND) + hk * ND;
    f32x8 a = *(const f32x8*)(kp + d0);
    f32x8 p = *(const f32x8*)(kp + (d0 ^ 64));
    const float* tr = tab + (size_t)(pos[tok] & 2047) * 128 + (d0 & 63);
    f32x8 c8 = *(const f32x8*)tr;
    f32x8 s8 = *(const f32x8*)(tr + 64);
    u16x8 o;
#pragma unroll
    for (int i = 0; i < 8; ++i) {
      float val = (d0 < 64) ? (a[i] * c8[i] - p[i] * s8[i])
                            : (a[i] * c8[i] + p[i] * s8[i]);
      o[i] = f2bf(val);
    }
    *(u16x8*)(kout + (size_t)u * 8) = o;
  }

  unsigned short* vout = vimg + (size_t)bid * 4096;
  {
    const int d0 = (t >> 2) << 1;     // even dim; thread covers d0, d0+1
    const int kp4 = t & 3;            // key sub-block (8 keys)
    const int tok0 = (b << 11) + (ti << 5) + (kp4 << 3);
    const float* vp = vin + (size_t)tok0 * (NHK * ND) + hk * ND + d0;
    u16x8 lo, hi;
#pragma unroll
    for (int i = 0; i < 8; ++i) {
      f32x2 r = *(const f32x2*)(vp + (size_t)i * (NHK * ND));
      lo[i] = f2bf(r[0]);
      hi[i] = f2bf(r[1]);
    }
    const int sub = kp4 ^ ((d0 >> 1) & 3);  // same for d0 and d0+1
    *(u16x8*)(vout + d0 * 32 + sub * 8) = lo;
    *(u16x8*)(vout + (d0 + 1) * 32 + sub * 8) = hi;
  }
}

// ---------------- fused flash attention (K in LDS, V direct-from-L2) -------------
// 256 thr = 4 waves (one per g). Wave owns 32 q-rows (2 halves of 16) x D=128.
// K double-buffered in LDS via global_load_lds; V fragments read straight from
// the L2-resident image (4 early / 4 late to bound register pressure).
template <bool PRE>
__global__ __launch_bounds__(256, 3) void attn_fwd(
    const float* __restrict__ qin, const float* __restrict__ kin,
    const float* __restrict__ vin, const int* __restrict__ pos,
    const char* __restrict__ kimg, const char* __restrict__ vimg,
    const float* __restrict__ tab, float* __restrict__ out) {
  __shared__ __align__(16) char Kb[2][8192];

  const int B = blockIdx.x;
  // XCD swizzle: all 64 q-tiles of a (b,hk) group land on one XCD; heavy tiles first
  const int group = (B & 7) + ((B >> 9) << 3);
  const int qt = 63 - ((B >> 3) & 63);
  const int hk = group & 7, b = group >> 3;

  const int tid = threadIdx.x;
  const int w = tid >> 6, lane = tid & 63, h = lane >> 4, ln = lane & 15;
  const int g = w;
  const int q0b = qt << 5;
  int lo = q0b - (NWIN - 1);
  if (lo < 0) lo = 0;
  lo &= ~31;
  const int ti0 = lo >> 5;
  const int nt = (q0b >> 5) - ti0 + 1;

  const size_t gbase = (size_t)group * 64 * 8192;
  const char* kg = PRE ? kimg + gbase + (size_t)(w * 128 + lane) * 16 : nullptr;
  const char* vgb = PRE ? vimg + gbase : nullptr;

  auto stage = [&](int sl, int ti) {
    if constexpr (PRE) {
      const char* ksrc = kg + (size_t)ti * 8192;
      char* kd = &Kb[sl][w * 2048];
      gll16(ksrc, kd);
      gll16(ksrc + 1024, kd + 1024);
    } else {
      // K: rope inline, swizzled writes
      const int j = tid >> 3;
      const int du = (tid & 7) << 4;
      const int tok = (b << 11) + (ti << 5) + j;
      const float* kp = kin + (size_t)tok * (NHK * ND) + hk * ND;
      const float pj = (float)pos[tok];
#pragma unroll
      for (int gq = 0; gq < 2; ++gq) {
        const int dd = du + gq * 8;
        f32x8 a = *(const f32x8*)(kp + dd);
        f32x8 p = *(const f32x8*)(kp + (dd ^ 64));
        u16x8 o;
#pragma unroll
        for (int i = 0; i < 8; ++i) {
          float s, c;
          __sincosf(pj * ex2(-(float)((dd & 63) + i) * L2_10K), &s, &c);
          float val = (dd < 64) ? (a[i] * c - p[i] * s) : (a[i] * c + p[i] * s);
          o[i] = f2bf(val);
        }
        *(u16x8*)(&Kb[sl][((j << 8) + (dd << 1)) ^ ((j & 7) << 4)]) = o;
      }
    }
  };

  // prologue: stage K tile 0 into slot 0 (overlaps Q rope)
  stage(0, ti0);

  // ---- Q fragments: rope + scale*log2e, bf16 (cos/sin from tab in PRE mode) ----
  const float QSC = 0.08838834764831845f * 1.4426950408889634f;
  bf16x8 qfr[2][4];
#pragma unroll
  for (int hf = 0; hf < 2; ++hf) {
    const int qrow = q0b + hf * 16 + ln;
    const size_t tokq = (size_t)(b << 11) + qrow;
    const float* qp = qin + tokq * 4096 + (hk * 4 + g) * 128;
    const int posq = pos[tokq] & 2047;
#pragma unroll
    for (int pp = 0; pp < 2; ++pp) {
      const int rr = (pp << 5) + (h << 3);
      f32x8 lo8 = *(const f32x8*)(qp + rr);
      f32x8 hi8 = *(const f32x8*)(qp + rr + 64);
      f32x8 cc, ss;
      if constexpr (PRE) {
        const float* tp = tab + (size_t)posq * 128 + rr;
        cc = *(const f32x8*)tp;
        ss = *(const f32x8*)(tp + 64);
      } else {
        const float pf = (float)posq;
#pragma unroll
        for (int i = 0; i < 8; ++i) {
          float s, c;
          __sincosf(pf * ex2(-(float)(rr + i) * L2_10K), &s, &c);
          cc[i] = c;
          ss[i] = s;
        }
      }
      u16x8 ulo, uhi;
#pragma unroll
      for (int i = 0; i < 8; ++i) {
        ulo[i] = f2bf((lo8[i] * cc[i] - hi8[i] * ss[i]) * QSC);
        uhi[i] = f2bf((hi8[i] * cc[i] + lo8[i] * ss[i]) * QSC);
      }
      qfr[hf][pp] = __builtin_bit_cast(bf16x8, ulo);
      qfr[hf][2 + pp] = __builtin_bit_cast(bf16x8, uhi);
    }
  }

  f32x4 Oc[2][8] = {};
  float msh[2] = {-1e30f, -1e30f};  // running max per q-row, replicated over h-groups
  float lsum[2] = {};               // per-lane partial sums
  const int sw = (ln & 7) << 4;
  // V frag byte offset within a db-block: row d=db*16+ln, phys chunk h^((ln>>1)&3)
  const int voff = (ln << 6) + ((h ^ ((ln >> 1) & 3)) << 4);

  for (int t = 0; t < nt; ++t) {
    asm volatile("s_waitcnt vmcnt(0)" ::: "memory");
    __syncthreads();  // K tile-t resident; all waves done with slot (t+1)&1
    if (t + 1 < nt) stage((t + 1) & 1, ti0 + t + 1);

    const int j0 = (ti0 + t) << 5;
    const char* KB = Kb[t & 1];
    const char* vt = PRE ? vgb + (size_t)(ti0 + t) * 8192 : nullptr;

    // ---- early V fragments (db 0..3): latency hides under QK + softmax ----
    bf16x8 vf[8];
    if constexpr (PRE) {
#pragma unroll
      for (int db = 0; db < 4; ++db)
        vf[db] = *(const bf16x8*)(vt + (db << 10) + voff);
    } else {
#pragma unroll
      for (int db = 0; db < 4; ++db) {
        u16x8 o;
#pragma unroll
        for (int i = 0; i < 8; ++i)
          o[i] = f2bf(vin[(size_t)((b << 11) + j0 + (h << 3) + i) * (NHK * ND) +
                          hk * ND + (db << 4) + ln]);
        vf[db] = __builtin_bit_cast(bf16x8, o);
      }
    }

    // ---- S^T = K Q^T: D[key][q], 2 key sub-tiles x 2 q halves ----
    f32x4 sT[2][2] = {};  // [qh][ki]
    __builtin_amdgcn_s_setprio(1);
#pragma unroll
    for (int c = 0; c < 4; ++c) {
      const bf16x8 k0 = *(const bf16x8*)(
          KB + (((ln << 8) + (c << 6) + (h << 4)) ^ sw));
      const bf16x8 k1 = *(const bf16x8*)(
          KB + ((((16 + ln) << 8) + (c << 6) + (h << 4)) ^ sw));
      sT[0][0] = MFMA16(k0, qfr[0][c], sT[0][0]);
      sT[0][1] = MFMA16(k1, qfr[0][c], sT[0][1]);
      sT[1][0] = MFMA16(k0, qfr[1][c], sT[1][0]);
      sT[1][1] = MFMA16(k1, qfr[1][c], sT[1][1]);
    }
    __builtin_amdgcn_s_setprio(0);

    // ---- mask only boundary tiles (wave-uniform branch) ----
    if ((j0 >= q0b) || (j0 < q0b - 992)) {
#pragma unroll
      for (int qh = 0; qh < 2; ++qh) {
        const int irow = q0b + qh * 16 + ln;
#pragma unroll
        for (int ki = 0; ki < 2; ++ki)
#pragma unroll
          for (int r = 0; r < 4; ++r) {
            const int j = j0 + ki * 16 + (h << 2) + r;
            if (!(j <= irow && irow - j < NWIN)) sT[qh][ki][r] = MASKV;
          }
      }
    }

    // ---- online softmax: deferred-max fast path (pure per-lane) ----
    float pm[2];
#pragma unroll
    for (int qh = 0; qh < 2; ++qh) {
      const f32x4 a0 = sT[qh][0], a1 = sT[qh][1];
      pm[qh] = fmaxf(fmaxf(fmaxf(a0[0], a0[1]), fmaxf(a0[2], a0[3])),
                     fmaxf(fmaxf(a1[0], a1[1]), fmaxf(a1[2], a1[3])));
    }
    const float ov = fmaxf(pm[0] - msh[0], pm[1] - msh[1]);
    if (__any(ov > 8.0f)) {  // slow path: true row max + rescale
#pragma unroll
      for (int qh = 0; qh < 2; ++qh) {
        float M = pm[qh];
        M = fmaxf(M, __shfl_xor(M, 16));
        M = fmaxf(M, __shfl_xor(M, 32));
        const float mn = fmaxf(msh[qh], M);
        const float co = ex2(msh[qh] - mn);
        msh[qh] = mn;
        lsum[qh] *= co;
        float coO[4];
#pragma unroll
        for (int r = 0; r < 4; ++r) coO[r] = __shfl(co, (h << 2) + r);
#pragma unroll
        for (int db = 0; db < 8; ++db)
#pragma unroll
          for (int r = 0; r < 4; ++r) Oc[qh][db][r] *= coO[r];
      }
    }

    bf16x8 pa[2];
#pragma unroll
    for (int qh = 0; qh < 2; ++qh) {
#pragma unroll
      for (int ki = 0; ki < 2; ++ki)
#pragma unroll
        for (int r = 0; r < 4; ++r)
          sT[qh][ki][r] = ex2(sT[qh][ki][r] - msh[qh]);
      lsum[qh] += ((sT[qh][0][0] + sT[qh][0][1]) + (sT[qh][0][2] + sT[qh][0][3])) +
                  ((sT[qh][1][0] + sT[qh][1][1]) + (sT[qh][1][2] + sT[qh][1][3]));
      unsigned int A = cvtpk(sT[qh][0][0], sT[qh][0][1]);
      unsigned int Bk = cvtpk(sT[qh][0][2], sT[qh][0][3]);
      unsigned int C = cvtpk(sT[qh][1][0], sT[qh][1][1]);
      unsigned int D = cvtpk(sT[qh][1][2], sT[qh][1][3]);
      asm volatile("v_permlane32_swap_b32 %0, %1" : "+v"(A), "+v"(C));
      asm volatile("v_permlane16_swap_b32 %0, %1" : "+v"(A), "+v"(C));
      asm volatile("v_permlane32_swap_b32 %0, %1" : "+v"(Bk), "+v"(D));
      asm volatile("v_permlane16_swap_b32 %0, %1" : "+v"(Bk), "+v"(D));
      u32x4 pk4 = {A, Bk, C, D};
      pa[qh] = __builtin_bit_cast(bf16x8, pk4);
    }

    // ---- late V fragments (db 4..7): latency hides under first PV MFMAs ----
    if constexpr (PRE) {
#pragma unroll
      for (int db = 4; db < 8; ++db)
        vf[db] = *(const bf16x8*)(vt + (db << 10) + voff);
    } else {
#pragma unroll
      for (int db = 4; db < 8; ++db) {
        u16x8 o;
#pragma unroll
        for (int i = 0; i < 8; ++i)
          o[i] = f2bf(vin[(size_t)((b << 11) + j0 + (h << 3) + i) * (NHK * ND) +
                          hk * ND + (db << 4) + ln]);
        vf[db] = __builtin_bit_cast(bf16x8, o);
      }
    }

    // ---- P V: O[q][d] += P[q][keys] V[keys][d] ----
    __builtin_amdgcn_s_setprio(1);
#pragma unroll
    for (int db = 0; db < 8; ++db) {
      Oc[0][db] = MFMA16(pa[0], vf[db], Oc[0][db]);
      Oc[1][db] = MFMA16(pa[1], vf[db], Oc[1][db]);
    }
    __builtin_amdgcn_s_setprio(0);
  }

  // ---- epilogue: full row-sum, redistribute, write ----
#pragma unroll
  for (int qh = 0; qh < 2; ++qh) {
    float ls = lsum[qh];
    ls += __shfl_xor(ls, 16);
    ls += __shfl_xor(ls, 32);
#pragma unroll
    for (int r = 0; r < 4; ++r) {
      const float rl = 1.0f / __shfl(ls, (h << 2) + r);
      const int irow = q0b + qh * 16 + (h << 2) + r;
      float* op = out + ((size_t)(b << 11) + irow) * 4096 + (hk * 4 + g) * 128 + ln;
#pragma unroll
      for (int db = 0; db < 8; ++db) op[db * 16] = Oc[qh][db][r] * rl;
    }
  }
}

extern "C" void kernel_launch(void* const* d_in, const int* in_sizes, int n_in,
                              void* d_out, int out_size, void* d_ws, size_t ws_size,
                              hipStream_t stream) {
  const float* q = (const float*)d_in[0];
  const float* k = (const float*)d_in[1];
  const float* v = (const float*)d_in[2];
  const int* pos = (const int*)d_in[3];
  float* out = (float*)d_out;

  const size_t TAB = (size_t)2048 * 128 * 4;        // 1MB cos/sin table
  const size_t KIMG = (size_t)16 * 64 * 8192;       // 8MB per image
  const size_t need = TAB + 2 * KIMG;

  if (ws_size >= need) {
    float* tab = (float*)d_ws;
    char* kimg = (char*)d_ws + TAB;
    char* vimg = kimg + KIMG;
    build_tab<<<2048, 64, 0, stream>>>(tab);
    prepass<<<1024, 256, 0, stream>>>(k, v, pos, tab,
                                      (unsigned short*)kimg, (unsigned short*)vimg);
    attn_fwd<true><<<1024, 256, 0, stream>>>(q, k, v, pos, kimg, vimg, tab, out);
  } else {
    attn_fwd<false><<<1024, 256, 0, stream>>>(q, k, v, pos, nullptr, nullptr, nullptr, out);
  }
}

// Round 10
// 95.128 us; speedup vs baseline: 1.4472x; 1.0863x over previous
//
#include <hip/hip_runtime.h>
#include <stdint.h>

#define NB 2
#define NS 2048
#define NHK 8
#define ND 128
#define NWIN 1024

using bf16x8 = __bf16 __attribute__((ext_vector_type(8)));
using f32x4  = float  __attribute__((ext_vector_type(4)));
using f32x2  = float  __attribute__((ext_vector_type(2)));
using f32x8  = float  __attribute__((ext_vector_type(8)));
using u16x8  = unsigned short __attribute__((ext_vector_type(8)));
using u32x4  = unsigned int   __attribute__((ext_vector_type(4)));

#define L2_10K (13.287712379549449f / 64.0f)  // log2(10000)/64
#define MASKV (-3.0e38f)

static __device__ __forceinline__ float ex2(float x) {
  return __builtin_amdgcn_exp2f(x);
}

static __device__ __forceinline__ unsigned short f2bf(float x) {
  unsigned int u = __builtin_bit_cast(unsigned int, x);
  u += 0x7FFFu + ((u >> 16) & 1u);
  return (unsigned short)(u >> 16);
}

static __device__ __forceinline__ unsigned int cvtpk(float lo, float hi) {
  unsigned int r;
  asm("v_cvt_pk_bf16_f32 %0, %1, %2" : "=v"(r) : "v"(lo), "v"(hi));
  return r;
}

static __device__ __forceinline__ void gll16(const void* g, void* l) {
  __builtin_amdgcn_global_load_lds(
      (const __attribute__((address_space(1))) void*)g,
      (__attribute__((address_space(3))) void*)l, 16, 0, 0);
}

#define MFMA16(a, b, c) __builtin_amdgcn_mfma_f32_16x16x32_bf16((a), (b), (c), 0, 0, 0)

// ---------------- cos/sin table: tab[p][0..63]=cos, [64..127]=sin ----------------
__global__ __launch_bounds__(64) void build_tab(float* __restrict__ tab) {
  const int p = blockIdx.x, f = threadIdx.x;
  float s, c;
  __sincosf((float)p * ex2(-(float)f * L2_10K), &s, &c);
  tab[(size_t)p * 128 + f] = c;
  tab[(size_t)p * 128 + 64 + f] = s;
}

// ---------------- prepass: per-tile K (roped, swizzled) and V ([d][key] swz) images ----
__global__ __launch_bounds__(256) void prepass(
    const float* __restrict__ kin, const float* __restrict__ vin,
    const int* __restrict__ pos, const float* __restrict__ tab,
    unsigned short* __restrict__ kimg, unsigned short* __restrict__ vimg) {
  const int bid = blockIdx.x;
  const int ti = bid & 63, gidx = bid >> 6;
  const int hk = gidx & 7, b = gidx >> 3;
  const int t = threadIdx.x;

  unsigned short* kout = kimg + (size_t)bid * 4096;
#pragma unroll
  for (int uu = 0; uu < 2; ++uu) {
    const int u = t * 2 + uu;
    const int j = u >> 4;
    const int d0 = ((u & 15) << 3) ^ ((j & 7) << 3);  // u16 index
    const int tok = (b << 11) + (ti << 5) + j;
    const float* kp = kin + (size_t)tok * (NHK * ND) + hk * ND;
    f32x8 a = *(const f32x8*)(kp + d0);
    f32x8 p = *(const f32x8*)(kp + (d0 ^ 64));
    const float* tr = tab + (size_t)(pos[tok] & 2047) * 128 + (d0 & 63);
    f32x8 c8 = *(const f32x8*)tr;
    f32x8 s8 = *(const f32x8*)(tr + 64);
    u16x8 o;
#pragma unroll
    for (int i = 0; i < 8; ++i) {
      float val = (d0 < 64) ? (a[i] * c8[i] - p[i] * s8[i])
                            : (a[i] * c8[i] + p[i] * s8[i]);
      o[i] = f2bf(val);
    }
    *(u16x8*)(kout + (size_t)u * 8) = o;
  }

  unsigned short* vout = vimg + (size_t)bid * 4096;
  {
    const int d0 = (t >> 2) << 1;     // even dim; thread covers d0, d0+1
    const int kp4 = t & 3;            // key sub-block (8 keys)
    const int tok0 = (b << 11) + (ti << 5) + (kp4 << 3);
    const float* vp = vin + (size_t)tok0 * (NHK * ND) + hk * ND + d0;
    u16x8 lo, hi;
#pragma unroll
    for (int i = 0; i < 8; ++i) {
      f32x2 r = *(const f32x2*)(vp + (size_t)i * (NHK * ND));
      lo[i] = f2bf(r[0]);
      hi[i] = f2bf(r[1]);
    }
    const int sub = kp4 ^ ((d0 >> 1) & 3);  // same for d0 and d0+1
    *(u16x8*)(vout + d0 * 32 + sub * 8) = lo;
    *(u16x8*)(vout + (d0 + 1) * 32 + sub * 8) = hi;
  }
}

// ---------------- fused flash attention (balanced 768-block grid) ----------------
// 768 blocks = 16 groups x 48 units; unit<16 -> light pair (qt=unit, 31-unit),
// else heavy single (qt=unit+16). Every block: exactly 33 tile-iterations.
// Kernel body per q-tile = R4 structure: 4 waves (one per g), 32 q-rows/wave,
// K+V double-buffered LDS via global_load_lds, swapped QK^T, in-register P.
template <bool PRE>
__global__ __launch_bounds__(256, 3) void attn_fwd(
    const float* __restrict__ qin, const float* __restrict__ kin,
    const float* __restrict__ vin, const int* __restrict__ pos,
    const char* __restrict__ kimg, const char* __restrict__ vimg,
    const float* __restrict__ tab, float* __restrict__ out) {
  __shared__ __align__(16) char Kb[2][8192];
  __shared__ __align__(16) char Vb[2][8192];

  const int B = blockIdx.x;
  const int xcd = B & 7;
  const int i96 = B >> 3;  // 0..95
  const int group = xcd + ((i96 >= 48) ? 8 : 0);
  const int unit = (i96 >= 48) ? i96 - 48 : i96;
  const int hk = group & 7, b = group >> 3;
  const int isPair = unit < 16;
  const int qtA = isPair ? unit : unit + 16;
  const int qtB = 31 - unit;  // only used when isPair

  const int tid = threadIdx.x;
  const int w = tid >> 6, lane = tid & 63, h = lane >> 4, ln = lane & 15;
  const int g = w;

  const size_t gbase = (size_t)group * 64 * 8192;
  const char* kg = PRE ? kimg + gbase + (size_t)(w * 128 + lane) * 16 : nullptr;
  const char* vg = PRE ? vimg + gbase + (size_t)(w * 128 + lane) * 16 : nullptr;

  auto stage = [&](int sl, int ti) {
    if constexpr (PRE) {
      const char* ksrc = kg + (size_t)ti * 8192;
      const char* vsrc = vg + (size_t)ti * 8192;
      char* kd = &Kb[sl][w * 2048];
      char* vd = &Vb[sl][w * 2048];
      gll16(ksrc, kd);
      gll16(ksrc + 1024, kd + 1024);
      gll16(vsrc, vd);
      gll16(vsrc + 1024, vd + 1024);
    } else {
      // K: rope inline, swizzled writes
      const int j = tid >> 3;
      const int du = (tid & 7) << 4;
      const int tok = (b << 11) + (ti << 5) + j;
      const float* kp = kin + (size_t)tok * (NHK * ND) + hk * ND;
      const float pj = (float)pos[tok];
#pragma unroll
      for (int gq = 0; gq < 2; ++gq) {
        const int dd = du + gq * 8;
        f32x8 a = *(const f32x8*)(kp + dd);
        f32x8 p = *(const f32x8*)(kp + (dd ^ 64));
        u16x8 o;
#pragma unroll
        for (int i = 0; i < 8; ++i) {
          float s, c;
          __sincosf(pj * ex2(-(float)((dd & 63) + i) * L2_10K), &s, &c);
          float val = (dd < 64) ? (a[i] * c - p[i] * s) : (a[i] * c + p[i] * s);
          o[i] = f2bf(val);
        }
        *(u16x8*)(&Kb[sl][((j << 8) + (dd << 1)) ^ ((j & 7) << 4)]) = o;
      }
      // V: pair-interleaved [d][key] with chunk swizzle
      const int d0 = (tid >> 2) << 1;
      const int kp4 = tid & 3;
      const float* vp = vin + (size_t)((b << 11) + (ti << 5) + (kp4 << 3)) * (NHK * ND) + hk * ND + d0;
      u16x8 lov, hiv;
#pragma unroll
      for (int i = 0; i < 8; ++i) {
        f32x2 r = *(const f32x2*)(vp + (size_t)i * (NHK * ND));
        lov[i] = f2bf(r[0]);
        hiv[i] = f2bf(r[1]);
      }
      const int sub = kp4 ^ ((d0 >> 1) & 3);
      unsigned short* vb16 = (unsigned short*)Vb[sl];
      *(u16x8*)(vb16 + d0 * 32 + sub * 8) = lov;
      *(u16x8*)(vb16 + (d0 + 1) * 32 + sub * 8) = hiv;
    }
  };

  const float QSC = 0.08838834764831845f * 1.4426950408889634f;
  const int sw = (ln & 7) << 4;
  const int vsub = (h ^ ((ln >> 1) & 3)) << 4;

#pragma unroll 1
  for (int seg = 0; seg < 2; ++seg) {
    if (seg == 1 && !isPair) break;
    const int qt = seg ? qtB : qtA;
    const int q0b = qt << 5;
    int lo = q0b - (NWIN - 1);
    if (lo < 0) lo = 0;
    lo &= ~31;
    const int ti0 = lo >> 5;
    const int nt = (q0b >> 5) - ti0 + 1;

    // all waves done reading previous segment's LDS before restaging slot 0
    __syncthreads();
    stage(0, ti0);

    // ---- Q fragments: rope + scale*log2e, bf16 (cos/sin from tab in PRE mode) ----
    bf16x8 qfr[2][4];
#pragma unroll
    for (int hf = 0; hf < 2; ++hf) {
      const int qrow = q0b + hf * 16 + ln;
      const size_t tokq = (size_t)(b << 11) + qrow;
      const float* qp = qin + tokq * 4096 + (hk * 4 + g) * 128;
      const int posq = pos[tokq] & 2047;
#pragma unroll
      for (int pp = 0; pp < 2; ++pp) {
        const int rr = (pp << 5) + (h << 3);
        f32x8 lo8 = *(const f32x8*)(qp + rr);
        f32x8 hi8 = *(const f32x8*)(qp + rr + 64);
        f32x8 cc, ss;
        if constexpr (PRE) {
          const float* tp = tab + (size_t)posq * 128 + rr;
          cc = *(const f32x8*)tp;
          ss = *(const f32x8*)(tp + 64);
        } else {
          const float pf = (float)posq;
#pragma unroll
          for (int i = 0; i < 8; ++i) {
            float s, c;
            __sincosf(pf * ex2(-(float)(rr + i) * L2_10K), &s, &c);
            cc[i] = c;
            ss[i] = s;
          }
        }
        u16x8 ulo, uhi;
#pragma unroll
        for (int i = 0; i < 8; ++i) {
          ulo[i] = f2bf((lo8[i] * cc[i] - hi8[i] * ss[i]) * QSC);
          uhi[i] = f2bf((hi8[i] * cc[i] + lo8[i] * ss[i]) * QSC);
        }
        qfr[hf][pp] = __builtin_bit_cast(bf16x8, ulo);
        qfr[hf][2 + pp] = __builtin_bit_cast(bf16x8, uhi);
      }
    }

    f32x4 Oc[2][8] = {};
    float msh[2] = {-1e30f, -1e30f};
    float lsum[2] = {};

#pragma unroll 1
    for (int t = 0; t < nt; ++t) {
      asm volatile("s_waitcnt vmcnt(0)" ::: "memory");
      __syncthreads();  // tile-t resident; all waves done with slot (t+1)&1
      if (t + 1 < nt) stage((t + 1) & 1, ti0 + t + 1);

      const int j0 = (ti0 + t) << 5;
      const char* KB = Kb[t & 1];

      // ---- S^T = K Q^T: D[key][q], 2 key sub-tiles x 2 q halves ----
      f32x4 sT[2][2] = {};  // [qh][ki]
      __builtin_amdgcn_s_setprio(1);
#pragma unroll
      for (int c = 0; c < 4; ++c) {
        const bf16x8 k0 = *(const bf16x8*)(
            KB + (((ln << 8) + (c << 6) + (h << 4)) ^ sw));
        const bf16x8 k1 = *(const bf16x8*)(
            KB + ((((16 + ln) << 8) + (c << 6) + (h << 4)) ^ sw));
        sT[0][0] = MFMA16(k0, qfr[0][c], sT[0][0]);
        sT[0][1] = MFMA16(k1, qfr[0][c], sT[0][1]);
        sT[1][0] = MFMA16(k0, qfr[1][c], sT[1][0]);
        sT[1][1] = MFMA16(k1, qfr[1][c], sT[1][1]);
      }
      __builtin_amdgcn_s_setprio(0);

      // ---- mask only boundary tiles (wave-uniform branch) ----
      if ((j0 >= q0b) || (j0 < q0b - 992)) {
#pragma unroll
        for (int qh = 0; qh < 2; ++qh) {
          const int irow = q0b + qh * 16 + ln;
#pragma unroll
          for (int ki = 0; ki < 2; ++ki)
#pragma unroll
            for (int r = 0; r < 4; ++r) {
              const int j = j0 + ki * 16 + (h << 2) + r;
              if (!(j <= irow && irow - j < NWIN)) sT[qh][ki][r] = MASKV;
            }
        }
      }

      // ---- online softmax: deferred-max fast path (pure per-lane) ----
      float pm[2];
#pragma unroll
      for (int qh = 0; qh < 2; ++qh) {
        const f32x4 a0 = sT[qh][0], a1 = sT[qh][1];
        pm[qh] = fmaxf(fmaxf(fmaxf(a0[0], a0[1]), fmaxf(a0[2], a0[3])),
                       fmaxf(fmaxf(a1[0], a1[1]), fmaxf(a1[2], a1[3])));
      }
      const float ov = fmaxf(pm[0] - msh[0], pm[1] - msh[1]);
      if (__any(ov > 8.0f)) {  // slow path: true row max + rescale
#pragma unroll
        for (int qh = 0; qh < 2; ++qh) {
          float M = pm[qh];
          M = fmaxf(M, __shfl_xor(M, 16));
          M = fmaxf(M, __shfl_xor(M, 32));
          const float mn = fmaxf(msh[qh], M);
          const float co = ex2(msh[qh] - mn);
          msh[qh] = mn;
          lsum[qh] *= co;
          float coO[4];
#pragma unroll
          for (int r = 0; r < 4; ++r) coO[r] = __shfl(co, (h << 2) + r);
#pragma unroll
          for (int db = 0; db < 8; ++db)
#pragma unroll
            for (int r = 0; r < 4; ++r) Oc[qh][db][r] *= coO[r];
        }
      }

      bf16x8 pa[2];
#pragma unroll
      for (int qh = 0; qh < 2; ++qh) {
#pragma unroll
        for (int ki = 0; ki < 2; ++ki)
#pragma unroll
          for (int r = 0; r < 4; ++r)
            sT[qh][ki][r] = ex2(sT[qh][ki][r] - msh[qh]);
        lsum[qh] += ((sT[qh][0][0] + sT[qh][0][1]) + (sT[qh][0][2] + sT[qh][0][3])) +
                    ((sT[qh][1][0] + sT[qh][1][1]) + (sT[qh][1][2] + sT[qh][1][3]));
        unsigned int A = cvtpk(sT[qh][0][0], sT[qh][0][1]);
        unsigned int Bk = cvtpk(sT[qh][0][2], sT[qh][0][3]);
        unsigned int C = cvtpk(sT[qh][1][0], sT[qh][1][1]);
        unsigned int D = cvtpk(sT[qh][1][2], sT[qh][1][3]);
        asm volatile("v_permlane32_swap_b32 %0, %1" : "+v"(A), "+v"(C));
        asm volatile("v_permlane16_swap_b32 %0, %1" : "+v"(A), "+v"(C));
        asm volatile("v_permlane32_swap_b32 %0, %1" : "+v"(Bk), "+v"(D));
        asm volatile("v_permlane16_swap_b32 %0, %1" : "+v"(Bk), "+v"(D));
        u32x4 pk4 = {A, Bk, C, D};
        pa[qh] = __builtin_bit_cast(bf16x8, pk4);
      }

      // ---- P V: O[q][d] += P[q][keys] V[keys][d] ----
      const char* VB = Vb[t & 1];
      __builtin_amdgcn_s_setprio(1);
#pragma unroll
      for (int db = 0; db < 8; ++db) {
        const bf16x8 vv = *(const bf16x8*)(VB + (db << 10) + (ln << 6) + vsub);
        Oc[0][db] = MFMA16(pa[0], vv, Oc[0][db]);
        Oc[1][db] = MFMA16(pa[1], vv, Oc[1][db]);
      }
      __builtin_amdgcn_s_setprio(0);
    }

    // ---- epilogue: full row-sum, redistribute, write ----
#pragma unroll
    for (int qh = 0; qh < 2; ++qh) {
      float ls = lsum[qh];
      ls += __shfl_xor(ls, 16);
      ls += __shfl_xor(ls, 32);
#pragma unroll
      for (int r = 0; r < 4; ++r) {
        const float rl = 1.0f / __shfl(ls, (h << 2) + r);
        const int irow = q0b + qh * 16 + (h << 2) + r;
        float* op = out + ((size_t)(b << 11) + irow) * 4096 + (hk * 4 + g) * 128 + ln;
#pragma unroll
        for (int db = 0; db < 8; ++db) op[db * 16] = Oc[qh][db][r] * rl;
      }
    }
  }
}

extern "C" void kernel_launch(void* const* d_in, const int* in_sizes, int n_in,
                              void* d_out, int out_size, void* d_ws, size_t ws_size,
                              hipStream_t stream) {
  const float* q = (const float*)d_in[0];
  const float* k = (const float*)d_in[1];
  const float* v = (const float*)d_in[2];
  const int* pos = (const int*)d_in[3];
  float* out = (float*)d_out;

  const size_t TAB = (size_t)2048 * 128 * 4;        // 1MB cos/sin table
  const size_t KIMG = (size_t)16 * 64 * 8192;       // 8MB per image
  const size_t need = TAB + 2 * KIMG;

  if (ws_size >= need) {
    float* tab = (float*)d_ws;
    char* kimg = (char*)d_ws + TAB;
    char* vimg = kimg + KIMG;
    build_tab<<<2048, 64, 0, stream>>>(tab);
    prepass<<<1024, 256, 0, stream>>>(k, v, pos, tab,
                                      (unsigned short*)kimg, (unsigned short*)vimg);
    attn_fwd<true><<<768, 256, 0, stream>>>(q, k, v, pos, kimg, vimg, tab, out);
  } else {
    attn_fwd<false><<<768, 256, 0, stream>>>(q, k, v, pos, nullptr, nullptr, nullptr, out);
  }
}